// Round 8
// baseline (120.368 us; speedup 1.0000x reference)
//
#include <hip/hip_runtime.h>
#include <stdint.h>

// LocallyConnected1d: out[b,c,o] = (1/8) * sum_{i<64,k<8} x[b,i,4o+k] * w[c,i,o,k]
// B=128, CIN=64, COUT=64, OUT_DIM=256, K=8, S=4, L=1028. fp32 in/out.
//
// R8: minimize chip-wide (L2/LLC-side) traffic: block = (q o-pair, b-half),
// grid 256, 512 threads. w read 2x chip-wide (vs 4x in R7), x ~2x. 8 i-chunks
// (i=8) with register-prefetch double-buffered LDS: loads for chunk n+1 issue
// before compute of chunk n; one barrier per chunk. Bl keeps the gs=i^(c&7)
// bank swizzle (uniform b128 reads); Al plane stride 776 el spreads banks.

#define B_    128
#define CIN_  64
#define COUT_ 64
#define OD_   256
#define K_    8
#define L_    1028

#define WPAR 8192          // Bl elems per parity: [o_lo 2][c 64][gs 8][k 8]
#define XPLN 776           // Al i-plane stride (el): 64*12 + 8 pad
#define XPAR (8 * XPLN)    // 6208 el per parity

typedef __attribute__((ext_vector_type(8))) short bf16x8;
typedef __attribute__((ext_vector_type(4))) short short4v;
typedef __attribute__((ext_vector_type(4))) float floatx4;

__device__ __forceinline__ unsigned short f32_to_bf16(float f) {
    union { float f; uint32_t u; } v; v.f = f;
    uint32_t u = v.u;
    u += 0x7FFFu + ((u >> 16) & 1u);   // round-to-nearest-even
    return (unsigned short)(u >> 16);
}

__global__ __launch_bounds__(512, 2)
void lc1d_r8(const float* __restrict__ x,
             const float* __restrict__ w,
             float* __restrict__ out) {
    __shared__ __align__(16) unsigned short Bl[2 * WPAR];  // 32 KB
    __shared__ __align__(16) unsigned short Al[2 * XPAR];  // 24.25 KB

    const int tid = threadIdx.x;
    const int blk = blockIdx.x;
    // XCD k hosts q in [16k,16k+16): one 128-B out-line = 16 q = one XCD's
    // range -> writes merge; x q-window overlap stays within the XCD's L2.
    const int q  = (blk & 7) * 16 + ((blk >> 3) & 15);
    const int bh = blk >> 7;            // 0..1
    const int b0 = bh * 64;

    const int wave = tid >> 6;          // 0..7
    const int lane = tid & 63;
    const int quad = lane >> 4;
    const int l16  = lane & 15;
    const int o_lo = wave & 1;
    const int ms   = wave >> 1;         // m-stripe (16 b rows), 0..3

    float4 wreg[4], xreg[4];

    // ---- load chunk ch into registers (coalesced, 8 float4/thread) ----
    auto load = [&](int ch) {
        const int i0 = ch * 8;
        #pragma unroll
        for (int it = 0; it < 4; ++it) {   // w: 64c x 8i runs of 16 floats
            const int u   = it * 512 + tid;
            const int t   = u & 3;
            const int run = u >> 2;        // 0..511
            const int iL  = run & 7;
            const int c   = run >> 3;      // 0..63
            wreg[it] = *(const float4*)(w +
                (size_t)(c * CIN_ + i0 + iL) * (OD_ * K_) + q * 16 + t * 4);
        }
        #pragma unroll
        for (int it = 0; it < 4; ++it) {   // x: 64b x 8i rows of 12 floats
            const int u   = it * 512 + tid;
            const int t   = u & 3;         // t==3 masked
            const int row = u >> 2;        // 0..511
            const int iL  = row & 7;
            const int b   = row >> 3;      // 0..63
            if (t < 3)
                xreg[it] = *(const float4*)(x +
                    (size_t)((b0 + b) * CIN_ + i0 + iL) * L_ + q * 8 + t * 4);
        }
    };

    // ---- convert + scatter registers into LDS[par] ----
    auto cvtstore = [&](int par) {
        #pragma unroll
        for (int it = 0; it < 4; ++it) {
            const int u   = it * 512 + tid;
            const int t   = u & 3;
            const int run = u >> 2;
            const int iL  = run & 7;
            const int c   = run >> 3;
            const float4 v = wreg[it];
            ushort4 sv = make_ushort4(f32_to_bf16(v.x), f32_to_bf16(v.y),
                                      f32_to_bf16(v.z), f32_to_bf16(v.w));
            const int olo = t >> 1;        // floats 4t..4t+3 = (o_lo, k-half)
            const int kh  = t & 1;
            const int gs  = iL ^ (c & 7);
            *(ushort4*)&Bl[par * WPAR + olo * 4096 + c * 64 + gs * 8 + kh * 4] = sv;
        }
        #pragma unroll
        for (int it = 0; it < 4; ++it) {
            const int u   = it * 512 + tid;
            const int t   = u & 3;
            const int row = u >> 2;
            const int iL  = row & 7;
            const int b   = row >> 3;
            if (t < 3) {
                const float4 v = xreg[it];
                ushort4 sv = make_ushort4(f32_to_bf16(v.x), f32_to_bf16(v.y),
                                          f32_to_bf16(v.z), f32_to_bf16(v.w));
                *(ushort4*)&Al[par * XPAR + iL * XPLN + b * 12 + t * 4] = sv;
            }
        }
    };

    floatx4 acc[4];
    #pragma unroll
    for (int nt = 0; nt < 4; ++nt) acc[nt] = (floatx4){0.f, 0.f, 0.f, 0.f};

    load(0);
    cvtstore(0);
    __syncthreads();

    for (int ch = 0; ch < 8; ++ch) {
        const int par = ch & 1;
        if (ch < 7) load(ch + 1);          // prefetch next chunk early

        #pragma unroll
        for (int kt = 0; kt < 2; ++kt) {   // chunk K = 64 = 2 steps of 32
            const int i_l = kt * 4 + quad; // 0..7
            const int ab  = par * XPAR + i_l * XPLN + (ms * 16 + l16) * 12 + o_lo * 4;
            const short4v a_lo = *(const short4v*)&Al[ab];      // k 0..3
            const short4v a_hi = *(const short4v*)&Al[ab + 4];  // k 4..7
            bf16x8 af;
            af[0] = a_lo[0]; af[1] = a_lo[1]; af[2] = a_lo[2]; af[3] = a_lo[3];
            af[4] = a_hi[0]; af[5] = a_hi[1]; af[6] = a_hi[2]; af[7] = a_hi[3];
            #pragma unroll
            for (int nt = 0; nt < 4; ++nt) {
                const int c  = nt * 16 + l16;
                const int gs = i_l ^ (c & 7);
                const bf16x8 bf = *(const bf16x8*)
                    &Bl[par * WPAR + o_lo * 4096 + c * 64 + gs * 8];
                acc[nt] = __builtin_amdgcn_mfma_f32_16x16x32_bf16(af, bf, acc[nt], 0, 0, 0);
            }
        }

        if (ch < 7) cvtstore(par ^ 1);     // waits vmcnt, fills other parity
        __syncthreads();
    }

    // ---- epilogue: D col=lane&15 (c), row=quad*4+reg (b); scale 1/sqrt(64) ----
    const int o_g = q * 2 + o_lo;
    #pragma unroll
    for (int nt = 0; nt < 4; ++nt) {
        const int c = nt * 16 + l16;
        #pragma unroll
        for (int r = 0; r < 4; ++r) {
            const int b = b0 + ms * 16 + quad * 4 + r;
            out[((size_t)b * COUT_ + c) * OD_ + o_g] = acc[nt][r] * 0.125f;
        }
    }
}

extern "C" void kernel_launch(void* const* d_in, const int* in_sizes, int n_in,
                              void* d_out, int out_size, void* d_ws, size_t ws_size,
                              hipStream_t stream) {
    const float* x = (const float*)d_in[0];   // (128, 64, 1028)
    const float* w = (const float*)d_in[1];   // (1, 64, 64, 256, 8)
    float* out = (float*)d_out;               // (128, 64, 256)
    hipLaunchKernelGGL(lc1d_r8, dim3(256), dim3(512), 0, stream, x, w, out);
}

// Round 9
// 117.372 us; speedup vs baseline: 1.0255x; 1.0255x over previous
//
#include <hip/hip_runtime.h>
#include <stdint.h>

// LocallyConnected1d: out[b,c,o] = (1/8) * sum_{i<64,k<8} x[b,i,4o+k] * w[c,i,o,k]
// B=128, CIN=64, COUT=64, OUT_DIM=256, K=8, S=4, L=1028. fp32 in/out.
//
// R9: dense-burst redesign. All prior rounds (40-50 us flat, all pipes idle)
// read x/w in 32-64 B bursts at ~4 KB strides -> ~1 TB/s effective. This
// round: block = (o-tile 8, b-tile 32, c-half 32), grid 256 x 512 threads.
// w reads = 256 B contiguous runs (8o x 8k per (c,i)); x reads = 144 B runs
// (36 floats per (b,i)). Wave = one o, 32x32x512 GEMM, 8 i-chunks,
// LDS double-buffered (100 KB), one barrier per chunk.

#define B_    128
#define CIN_  64
#define COUT_ 64
#define OD_   256
#define K_    8
#define L_    1028

#define XROW 36      // x im2col row: 36 bf16 el (8*4+4 floats), stride 18 dw

typedef __attribute__((ext_vector_type(8))) short bf16x8;
typedef __attribute__((ext_vector_type(4))) short short4v;
typedef __attribute__((ext_vector_type(4))) float floatx4;

__device__ __forceinline__ unsigned short f32_to_bf16(float f) {
    union { float f; uint32_t u; } v; v.f = f;
    uint32_t u = v.u;
    u += 0x7FFFu + ((u >> 16) & 1u);   // round-to-nearest-even
    return (unsigned short)(u >> 16);
}

__global__ __launch_bounds__(512, 2)
void lc1d_r9(const float* __restrict__ x,
             const float* __restrict__ w,
             float* __restrict__ out) {
    // Bw[par][i 8][c 32][o_sw 8][k 8] bf16, o_sw = ow ^ (c&7): 2x32 KB
    __shared__ __align__(16) unsigned short Bw[2][16384];
    // Al[par][i 8][b 32][36]: 2x18 KB
    __shared__ __align__(16) unsigned short Al[2][8 * 32 * XROW];

    const int tid = threadIdx.x;
    const int blk = blockIdx.x;
    // XCD m hosts o-tiles 4m..4m+3 = o 32m..32m+31 (one 128-B out-line group);
    // the 4 b-tile blocks of an (o-tile, c-half) colocate -> w L2-dedup.
    const int ot = (blk & 7) * 4 + ((blk >> 3) & 3);   // 0..31
    const int bt = (blk >> 5) & 3;
    const int ch2 = blk >> 7;                          // c half
    const int o0 = ot * 8;
    const int b0 = bt * 32;
    const int c0 = ch2 * 32;

    const int wave = tid >> 6;     // = ow, this wave's o within the tile (0..7)
    const int lane = tid & 63;
    const int quad = lane >> 4;
    const int l16  = lane & 15;
    const int ow   = wave;

    float4 wreg[8];
    float4 xreg[4], xtail;

    // ---- global loads for i-chunk ic (dense bursts) ----
    auto load = [&](int ic) {
        const int i0 = ic * 8;
        #pragma unroll
        for (int it = 0; it < 8; ++it) {     // w: 32c x 8i runs of 64 floats (256 B)
            const int u   = it * 512 + tid;
            const int t   = u & 15;          // float4 within run
            const int run = u >> 4;          // 0..255
            const int iL  = run & 7;
            const int c   = run >> 3;        // 0..31
            wreg[it] = *(const float4*)(w +
                (size_t)((c0 + c) * CIN_ + i0 + iL) * (OD_ * K_) + o0 * K_ + t * 4);
        }
        #pragma unroll
        for (int it = 0; it < 4; ++it) {     // x: 32b x 8i rows of 36 floats (144 B)
            const int u   = it * 512 + tid;
            const int t   = u & 7;           // float4 0..7
            const int row = u >> 3;          // 0..255
            const int iL  = row & 7;
            const int b   = row >> 3;
            xreg[it] = *(const float4*)(x +
                (size_t)((b0 + b) * CIN_ + i0 + iL) * L_ + o0 * 4 + t * 4);
        }
        if (tid < 256) {                      // tail float4 t=8 (floats 32..35)
            const int iL = tid & 7;
            const int b  = tid >> 3;
            xtail = *(const float4*)(x +
                (size_t)((b0 + b) * CIN_ + i0 + iL) * L_ + o0 * 4 + 32);
        }
    };

    // ---- convert + scatter into LDS parity par ----
    auto cvtstore = [&](int par) {
        #pragma unroll
        for (int it = 0; it < 8; ++it) {
            const int u   = it * 512 + tid;
            const int t   = u & 15;
            const int run = u >> 4;
            const int iL  = run & 7;
            const int c   = run >> 3;
            const float4 v = wreg[it];
            ushort4 sv = make_ushort4(f32_to_bf16(v.x), f32_to_bf16(v.y),
                                      f32_to_bf16(v.z), f32_to_bf16(v.w));
            const int o_r = t >> 1;           // o within tile
            const int kh  = t & 1;
            const int osw = o_r ^ (c & 7);    // bank swizzle baked into position
            *(ushort4*)&Bw[par][((iL * 32 + c) * 8 + osw) * 8 + kh * 4] = sv;
        }
        #pragma unroll
        for (int it = 0; it < 4; ++it) {
            const int u   = it * 512 + tid;
            const int t   = u & 7;
            const int row = u >> 3;
            const int iL  = row & 7;
            const int b   = row >> 3;
            const float4 v = xreg[it];
            ushort4 sv = make_ushort4(f32_to_bf16(v.x), f32_to_bf16(v.y),
                                      f32_to_bf16(v.z), f32_to_bf16(v.w));
            *(ushort4*)&Al[par][(iL * 32 + b) * XROW + t * 4] = sv;
        }
        if (tid < 256) {
            const int iL = tid & 7;
            const int b  = tid >> 3;
            ushort4 sv = make_ushort4(f32_to_bf16(xtail.x), f32_to_bf16(xtail.y),
                                      f32_to_bf16(xtail.z), f32_to_bf16(xtail.w));
            *(ushort4*)&Al[par][(iL * 32 + b) * XROW + 32] = sv;
        }
    };

    floatx4 acc[2][2];
    #pragma unroll
    for (int mt = 0; mt < 2; ++mt)
        #pragma unroll
        for (int ct = 0; ct < 2; ++ct) acc[mt][ct] = (floatx4){0.f, 0.f, 0.f, 0.f};

    load(0);
    cvtstore(0);
    __syncthreads();

    for (int ic = 0; ic < 8; ++ic) {
        const int par = ic & 1;
        if (ic < 7) load(ic + 1);            // dense global loads in flight

        // compute: chunk K = 8i x 8k = 64 = 2 k-steps of 32
        #pragma unroll
        for (int kt = 0; kt < 2; ++kt) {
            const int i_l = kt * 4 + quad;   // 0..7
            bf16x8 af[2];
            #pragma unroll
            for (int mt = 0; mt < 2; ++mt) {
                const int ab = (i_l * 32 + mt * 16 + l16) * XROW + ow * 4;
                const short4v a_lo = *(const short4v*)&Al[par][ab];      // k 0..3
                const short4v a_hi = *(const short4v*)&Al[par][ab + 4];  // k 4..7
                af[mt][0] = a_lo[0]; af[mt][1] = a_lo[1];
                af[mt][2] = a_lo[2]; af[mt][3] = a_lo[3];
                af[mt][4] = a_hi[0]; af[mt][5] = a_hi[1];
                af[mt][6] = a_hi[2]; af[mt][7] = a_hi[3];
            }
            #pragma unroll
            for (int ct = 0; ct < 2; ++ct) {
                const int cL  = ct * 16 + l16;            // c-local 0..31
                const int osw = ow ^ (cL & 7);            // c&7 == cL&7 (c0%32==0)
                const bf16x8 bf = *(const bf16x8*)&Bw[par][((i_l * 32 + cL) * 8 + osw) * 8];
                #pragma unroll
                for (int mt = 0; mt < 2; ++mt)
                    acc[mt][ct] = __builtin_amdgcn_mfma_f32_16x16x32_bf16(
                        af[mt], bf, acc[mt][ct], 0, 0, 0);
            }
        }

        if (ic < 7) cvtstore(par ^ 1);       // waits vmcnt, fills other parity
        __syncthreads();
    }

    // ---- epilogue: D col=lane&15 (c), row=quad*4+reg (b); scale 1/sqrt(64) ----
    const int o_g = o0 + ow;
    #pragma unroll
    for (int mt = 0; mt < 2; ++mt) {
        #pragma unroll
        for (int ct = 0; ct < 2; ++ct) {
            const int c = c0 + ct * 16 + l16;
            #pragma unroll
            for (int r = 0; r < 4; ++r) {
                const int b = b0 + mt * 16 + quad * 4 + r;
                out[((size_t)b * COUT_ + c) * OD_ + o_g] = acc[mt][ct][r] * 0.125f;
            }
        }
    }
}

extern "C" void kernel_launch(void* const* d_in, const int* in_sizes, int n_in,
                              void* d_out, int out_size, void* d_ws, size_t ws_size,
                              hipStream_t stream) {
    const float* x = (const float*)d_in[0];   // (128, 64, 1028)
    const float* w = (const float*)d_in[1];   // (1, 64, 64, 256, 8)
    float* out = (float*)d_out;               // (128, 64, 256)
    hipLaunchKernelGGL(lc1d_r9, dim3(256), dim3(512), 0, stream, x, w, out);
}